// Round 14
// baseline (198.277 us; speedup 1.0000x reference)
//
#include <hip/hip_runtime.h>
#include <stdint.h>

#define B_   8
#define CIN  8
#define COUT 32
#define H_   128
#define W_   128
#define OH   126
#define OW   126
#define TW   32
#define TH   4
#define XW   (TW + 4)   // 36
#define XH   (TH + 4)   // 8
#define YW   (TW + 2)   // 34
#define YH   (TH + 2)   // 6
#define NTJ  4
#define NTI  32         // ceil(126/4)
#define NPIXT (TH * TW) // 128 output pixels per block

// Constant-address-space view of a uniform global pointer: tells the AMDGPU
// backend the load is uniform+invariant -> s_load into SGPRs (scalar pipe,
// K$), folded as scalar operands into VALU. Round-13 lesson: weights via LDS
// cost 18 ds_read_b128/iter (LDS-throughput-bound, 65us); weights via plain
// global pointer cost per-lane global_loads + 64b address VALU (rounds 1-11).
typedef const __attribute__((address_space(4))) float cfloat;
__device__ __forceinline__ const cfloat* as_const(const float* p) {
  return (const cfloat*)(uintptr_t)p;
}

__global__ __launch_bounds__(256) void fused_kernel(
    const float* __restrict__ x, const float* __restrict__ w,
    const float* __restrict__ bias, float* __restrict__ out) {
  __shared__ float xs[CIN][XH][XW];   // 9216 B
  __shared__ float ys[CIN][YH][YW];   // 6528 B
  __shared__ float red[NPIXT];        // 512 B   (total 16256 B)

  const cfloat* wq = as_const(w);
  const cfloat* bq = as_const(bias);

  int tid = threadIdx.x;
  int blk = blockIdx.x;
  int tj0 = (blk % NTJ) * TW;
  int ti0 = ((blk / NTJ) % NTI) * TH;
  int b   = blk / (NTJ * NTI);

  // ---- Phase A: stage x tile ----
  const float* xb = x + (long)b * CIN * H_ * W_;
#pragma unroll 1
  for (int e = tid; e < CIN * XH * XW; e += 256) {   // 2304 elems, 9 passes
    int cc = e % XW;
    int rr = (e / XW) % XH;
    int ci = e / (XW * XH);
    int gi = ti0 + rr; if (gi > H_ - 1) gi = H_ - 1; // clamp (masked later)
    int gj = tj0 + cc; if (gj > W_ - 1) gj = W_ - 1;
    xs[ci][rr][cc] = xb[(ci * H_ + gi) * W_ + gj];
  }
  __syncthreads();

  // ---- Phase B: conv + bias -> ys (204 pixels, threads 0..203) ----
  if (tid < YH * YW) {
    int yr = tid / YW;
    int yc = tid % YW;
    float xv[CIN][3][3];
#pragma unroll
    for (int ci = 0; ci < CIN; ++ci)
#pragma unroll
      for (int kh = 0; kh < 3; ++kh)
#pragma unroll
        for (int kw = 0; kw < 3; ++kw)
          xv[ci][kh][kw] = xs[ci][yr + kh][yc + kw];

#pragma unroll 1
    for (int c = 0; c < CIN; ++c) {      // unroll 1: 72 weight SGPRs live
      const cfloat* wc = wq + c * (CIN * 9);   // uniform -> s_load
      float acc = bq[c];
#pragma unroll
      for (int ci = 0; ci < CIN; ++ci)
#pragma unroll
        for (int kh = 0; kh < 3; ++kh)
#pragma unroll
          for (int kw = 0; kw < 3; ++kw)
            acc = fmaf(xv[ci][kh][kw], wc[ci * 9 + kh * 3 + kw], acc);
      ys[c][yr][yc] = acc;
    }
  }
  __syncthreads();

  // ---- Phase C: stage2; 2 threads per pixel, 16 o's each ----
  int pix  = tid & (NPIXT - 1);                           // 0..127
  int half = __builtin_amdgcn_readfirstlane(tid >> 7);    // wave-uniform 0/1
  int ti = pix >> 5;                 // 0..3
  int tj = pix & 31;                 // 0..31
  int i = ti0 + ti, j = tj0 + tj;

  float tv[CIN][9];
#pragma unroll
  for (int c = 0; c < CIN; ++c)
#pragma unroll
    for (int kh = 0; kh < 3; ++kh)
#pragma unroll
      for (int kw = 0; kw < 3; ++kw)
        tv[c][kh * 3 + kw] = ys[c][ti + kh][tj + kw];

  bool v1h = (i + 1) < OH, v2h = (i + 2) < OH;
  bool v1w = (j + 1) < OW, v2w = (j + 2) < OW;
  bool vt1 = v1w, vt2 = v2w;
  bool vt3 = v1h, vt4 = v1h && v1w, vt5 = v1h && v2w;
  bool vt6 = v2h, vt7 = v2h && v1w, vt8 = v2h && v2w;

  const float NI = -__builtin_inff();
  float mn = __builtin_inff();

#pragma unroll 1
  for (int oo = 0; oo < COUT / 2; ++oo) {  // unroll 1: 72 weight SGPRs live
    const cfloat* wo = wq + (half * (COUT / 2) + oo) * (CIN * 9);  // s_load
    float m[9];
#pragma unroll
    for (int k = 0; k < 9; ++k) {
      float p0 = tv[0][k] * wo[0 * 9 + k];   // v_mul with 1 sgpr src: legal
      float p1 = tv[1][k] * wo[1 * 9 + k];
      float p2 = tv[2][k] * wo[2 * 9 + k];
      float p3 = tv[3][k] * wo[3 * 9 + k];
      float p4 = tv[4][k] * wo[4 * 9 + k];
      float p5 = tv[5][k] * wo[5 * 9 + k];
      float p6 = tv[6][k] * wo[6 * 9 + k];
      float p7 = tv[7][k] * wo[7 * 9 + k];
      float t0 = fmaxf(fmaxf(p0, p1), p2);   // 3-ary -> v_max3
      float t1 = fmaxf(fmaxf(p3, p4), p5);
      float t2 = fmaxf(p6, p7);
      m[k] = fmaxf(fmaxf(t0, t1), t2);
    }
    float z1 = vt1 ? m[1] : NI, z2 = vt2 ? m[2] : NI, z3 = vt3 ? m[3] : NI;
    float z4 = vt4 ? m[4] : NI, z5 = vt5 ? m[5] : NI, z6 = vt6 ? m[6] : NI;
    float z7 = vt7 ? m[7] : NI, z8 = vt8 ? m[8] : NI;
    float u0 = fmaxf(fmaxf(m[0], z1), z2);
    float u1 = fmaxf(fmaxf(z3, z4), z5);
    float u2 = fmaxf(fmaxf(z6, z7), z8);
    float mx = fmaxf(fmaxf(u0, u1), u2);
    mn = fminf(mn, mx);
  }

  // pairwise min-reduce across the two halves
  if (half == 1) red[pix] = mn;
  __syncthreads();
  if (half == 0) {
    float r = fminf(mn, red[pix]);
    if (i < OH && j < OW) out[(b * OH + i) * OW + j] = 2.0f * r;
  }
}

extern "C" void kernel_launch(void* const* d_in, const int* in_sizes, int n_in,
                              void* d_out, int out_size, void* d_ws, size_t ws_size,
                              hipStream_t stream) {
  const float* x    = (const float*)d_in[0];  // (8,8,128,128)
  const float* w    = (const float*)d_in[1];  // (32,8,3,3)
  const float* bias = (const float*)d_in[2];  // (32,)
  float* out = (float*)d_out;                 // (8,1,126,126) fp32

  const int blocks = B_ * NTI * NTJ;          // 1024 tiles
  fused_kernel<<<blocks, 256, 0, stream>>>(x, w, bias, out);
}

// Round 15
// 103.414 us; speedup vs baseline: 1.9173x; 1.9173x over previous
//
#include <hip/hip_runtime.h>

#define B_   8
#define CIN  8
#define COUT 32
#define H_   128
#define W_   128
#define OH   126
#define OW   126
#define TW   32
#define TH   4
#define XW   (TW + 4)   // 36
#define XH   (TH + 4)   // 8
#define YW   (TW + 2)   // 34
#define YH   (TH + 2)   // 6
#define NTJ  4
#define NTI  32         // ceil(126/4)
#define NPIXT (TH * TW) // 128 output pixels per block

// Structure (round-15): weights live in per-lane VGPRs, taps broadcast.
//  - Lane l owns output channel o = l&31 -> w[o][72] in 72 VGPRs, loaded ONCE
//    per block from global (L2-hot, 9KB total). Kills R13's per-iteration
//    broadcast weight refetch (288 ds_read_b128/wave) + its 72-reg churn.
//  - Phase C: wave = one tile row (ti = wave id), 2 adjacent pixels per iter
//    (half-wave each; 2 distinct broadcast addrs = free, m136). Taps come
//    from ys[r][col][c] (pixel-major, channel-minor) as 2 aligned float4
//    LDS reads per position -> 8 channels to all 32 o-lanes per instr pair.
//  - min over o = 5x __shfl_xor within 32-lane halves (no LDS, no o-loop).
//  - VALU-issue evidence: R11/R14 (global/AS4 weights) both 58us issue;
//    R13 (LDS) 23us. This removes R13's remaining operand traffic.
__global__ __launch_bounds__(256) void fused_kernel(
    const float* __restrict__ x, const float* __restrict__ w,
    const float* __restrict__ bias, float* __restrict__ out) {
  __shared__ float xs[CIN][XH][XW];                 // 9216 B
  __shared__ __align__(16) float ys[YH][YW][CIN];   // 6528 B pixel-major
  __shared__ float ws[CIN * CIN * 9];               // 2304 B conv weights (o<8)
  __shared__ float red[NPIXT];                      // 512 B

  int tid = threadIdx.x;
  int blk = blockIdx.x;
  int tj0 = (blk % NTJ) * TW;
  int ti0 = ((blk / NTJ) % NTI) * TH;
  int b   = blk / (NTJ * NTI);

  // ---- Phase A: stage x tile + conv weights ----
  const float* xb = x + (long)b * CIN * H_ * W_;
#pragma unroll 1
  for (int e = tid; e < CIN * XH * XW; e += 256) {   // 2304 elems
    int cc = e % XW;
    int rr = (e / XW) % XH;
    int ci = e / (XW * XH);
    int gi = ti0 + rr; if (gi > H_ - 1) gi = H_ - 1; // clamp (masked later)
    int gj = tj0 + cc; if (gj > W_ - 1) gj = W_ - 1;
    xs[ci][rr][cc] = xb[(ci * H_ + gi) * W_ + gj];
  }
#pragma unroll 1
  for (int e = tid; e < CIN * CIN * 9; e += 256) ws[e] = w[e];  // 576
  __syncthreads();

  // ---- Phase B: conv + bias -> ys (204 pixels, threads 0..203) ----
  if (tid < YH * YW) {
    int yr = tid / YW;
    int yc = tid % YW;
    float xv[CIN][3][3];
#pragma unroll
    for (int ci = 0; ci < CIN; ++ci)
#pragma unroll
      for (int kh = 0; kh < 3; ++kh)
#pragma unroll
        for (int kw = 0; kw < 3; ++kw)
          xv[ci][kh][kw] = xs[ci][yr + kh][yc + kw];

#pragma unroll 1
    for (int c = 0; c < CIN; ++c) {      // unroll 1: 72 weight values live
      const float* wc = &ws[c * (CIN * 9)];
      float acc = bias[c];
#pragma unroll
      for (int ci = 0; ci < CIN; ++ci)
#pragma unroll
        for (int kh = 0; kh < 3; ++kh)
#pragma unroll
          for (int kw = 0; kw < 3; ++kw)
            acc = fmaf(xv[ci][kh][kw], wc[ci * 9 + kh * 3 + kw], acc);
      ys[yr][yc][c] = acc;
    }
  }
  __syncthreads();

  // ---- Phase A': per-lane weight registers (o = lane&31) ----
  int lane = tid & 63;
  int wv   = tid >> 6;               // wave id 0..3 = tile row
  int olane = lane & 31;
  float wreg[COUT ? CIN * 9 : 0];    // 72 VGPRs, static indexing only
  {
    const float* wb = w + olane * (CIN * 9);
#pragma unroll
    for (int q = 0; q < 18; ++q) {
      float4 v = *reinterpret_cast<const float4*>(wb + q * 4);
      wreg[q * 4 + 0] = v.x; wreg[q * 4 + 1] = v.y;
      wreg[q * 4 + 2] = v.z; wreg[q * 4 + 3] = v.w;
    }
  }

  // ---- Phase C: 2 pixels per wave-iter, o spread across 32 lanes ----
  int halfp = lane >> 5;             // which pixel of the pair
  int i = ti0 + wv;                  // global row (wave-uniform)
  bool v1h = (i + 1) < OH, v2h = (i + 2) < OH;
  const float NI = -__builtin_inff();

#pragma unroll 1
  for (int it = 0; it < TW / 2; ++it) {
    int tj = 2 * it + halfp;
    int j = tj0 + tj;
    bool v1w = (j + 1) < OW, v2w = (j + 2) < OW;

    float acc = NI;
#pragma unroll
    for (int kh = 0; kh < 3; ++kh) {
#pragma unroll
      for (int kw = 0; kw < 3; ++kw) {
        const float* tp = &ys[wv + kh][tj + kw][0];
        float4 ta = *reinterpret_cast<const float4*>(tp);      // c 0..3
        float4 tb = *reinterpret_cast<const float4*>(tp + 4);  // c 4..7
        const int k = kh * 3 + kw;
        float p0 = ta.x * wreg[0 * 9 + k];
        float p1 = ta.y * wreg[1 * 9 + k];
        float p2 = ta.z * wreg[2 * 9 + k];
        float p3 = ta.w * wreg[3 * 9 + k];
        float p4 = tb.x * wreg[4 * 9 + k];
        float p5 = tb.y * wreg[5 * 9 + k];
        float p6 = tb.z * wreg[6 * 9 + k];
        float p7 = tb.w * wreg[7 * 9 + k];
        float t0 = fmaxf(fmaxf(p0, p1), p2);   // 3-ary -> v_max3
        float t1 = fmaxf(fmaxf(p3, p4), p5);
        float t2 = fmaxf(p6, p7);
        float pk = fmaxf(fmaxf(t0, t1), t2);
        bool valid = (kh == 0 || (kh == 1 ? v1h : v2h)) &&
                     (kw == 0 || (kw == 1 ? v1w : v2w));
        if (kh == 0 && kw == 0) acc = pk;
        else                    acc = fmaxf(acc, valid ? pk : NI);
      }
    }

    // min over o: butterfly within each 32-lane half
    acc = fminf(acc, __shfl_xor(acc, 1));
    acc = fminf(acc, __shfl_xor(acc, 2));
    acc = fminf(acc, __shfl_xor(acc, 4));
    acc = fminf(acc, __shfl_xor(acc, 8));
    acc = fminf(acc, __shfl_xor(acc, 16));
    if ((lane & 31) == 0) red[wv * TW + tj] = acc;
  }
  __syncthreads();

  // ---- coalesced output ----
  if (tid < NPIXT) {
    int pi = ti0 + (tid >> 5);
    int pj = tj0 + (tid & 31);
    if (pi < OH && pj < OW) out[(b * OH + pi) * OW + pj] = 2.0f * red[tid];
  }
}

extern "C" void kernel_launch(void* const* d_in, const int* in_sizes, int n_in,
                              void* d_out, int out_size, void* d_ws, size_t ws_size,
                              hipStream_t stream) {
  const float* x    = (const float*)d_in[0];  // (8,8,128,128)
  const float* w    = (const float*)d_in[1];  // (32,8,3,3)
  const float* bias = (const float*)d_in[2];  // (32,)
  float* out = (float*)d_out;                 // (8,1,126,126) fp32

  const int blocks = B_ * NTI * NTJ;          // 1024 tiles
  fused_kernel<<<blocks, 256, 0, stream>>>(x, w, bias, out);
}

// Round 16
// 83.348 us; speedup vs baseline: 2.3789x; 1.2407x over previous
//
#include <hip/hip_runtime.h>

#define B_   8
#define CIN  8
#define COUT 32
#define H_   128
#define W_   128
#define OH   126
#define OW   126
#define TW   32
#define TH   4
#define XW   (TW + 4)   // 36
#define XH   (TH + 4)   // 8
#define YW   (TW + 2)   // 34
#define YH   (TH + 2)   // 6
#define NTJ  4
#define NTI  32

// Forced scalar-pipe weight loads. R9-R14 lesson: the compiler never emits
// s_load for weights from a global pointer (per-lane global_load + 64b addr
// VALU instead, ~58us VALU-issue), and LDS weight/tap broadcasts serialize
// the LDS pipe (R13/R15: 288 b128-broadcasts per 64px, ~30us). s_load puts
// the 72 weights of one output channel in SGPRs; v_mul/v_fma fold 1 SGPR
// source free, so the o-loop body is pure VALU with zero LDS traffic.
typedef __attribute__((ext_vector_type(16))) float fx16;
typedef __attribute__((ext_vector_type(8)))  float fx8;
struct W72 { fx16 a, b, c, d; fx8 e; };

__device__ __forceinline__ W72 sload_w72(const float* p) {
  W72 r;
  asm volatile(
      "s_load_dwordx16 %0, %5, 0x0\n\t"
      "s_load_dwordx16 %1, %5, 0x40\n\t"
      "s_load_dwordx16 %2, %5, 0x80\n\t"
      "s_load_dwordx16 %3, %5, 0xc0\n\t"
      "s_load_dwordx8  %4, %5, 0x100\n\t"
      "s_waitcnt lgkmcnt(0)"
      : "=s"(r.a), "=s"(r.b), "=s"(r.c), "=s"(r.d), "=s"(r.e)
      : "s"(p));
  return r;
}
__device__ __forceinline__ float wg(const W72& w, int k) {  // k const after unroll
  return k < 16 ? w.a[k]
       : k < 32 ? w.b[k - 16]
       : k < 48 ? w.c[k - 32]
       : k < 64 ? w.d[k - 48]
                : w.e[k - 64];
}

__global__ __launch_bounds__(256) void fused_kernel(
    const float* __restrict__ x, const float* __restrict__ w,
    const float* __restrict__ bias, float* __restrict__ out) {
  __shared__ float xs[CIN][XH][XW];   // 9216 B
  __shared__ float ys[CIN][YH][YW];   // 6528 B channel-major
  __shared__ float bs[CIN];           // 32 B

  int tid = threadIdx.x;
  int blk = blockIdx.x;
  int tj0 = (blk % NTJ) * TW;
  int ti0 = ((blk / NTJ) % NTI) * TH;
  int b   = blk / (NTJ * NTI);

  // ---- Phase A: stage x tile (+bias) ----
  const float* xb = x + (long)b * CIN * H_ * W_;
#pragma unroll 1
  for (int e = tid; e < CIN * XH * XW; e += 256) {
    int cc = e % XW;
    int rr = (e / XW) % XH;
    int ci = e / (XW * XH);
    int gi = ti0 + rr; if (gi > H_ - 1) gi = H_ - 1;  // clamp (masked later)
    int gj = tj0 + cc; if (gj > W_ - 1) gj = W_ - 1;
    xs[ci][rr][cc] = xb[(ci * H_ + gi) * W_ + gj];
  }
  if (tid < CIN) bs[tid] = bias[tid];
  __syncthreads();

  // ---- Phase B: conv + bias -> ys; lane=pixel, weights via s_load ----
  if (tid < YH * YW) {
    int yr = tid / YW;
    int yc = tid % YW;
    float xv[CIN][9];
#pragma unroll
    for (int ci = 0; ci < CIN; ++ci)
#pragma unroll
      for (int kh = 0; kh < 3; ++kh)
#pragma unroll
        for (int kw = 0; kw < 3; ++kw)
          xv[ci][kh * 3 + kw] = xs[ci][yr + kh][yc + kw];

#pragma unroll 1
    for (int c = 0; c < CIN; ++c) {       // 72 weight SGPRs live per iter
      W72 wc = sload_w72(w + c * (CIN * 9));
      float acc = bs[c];
#pragma unroll
      for (int ci = 0; ci < CIN; ++ci)
#pragma unroll
        for (int k = 0; k < 9; ++k)
          acc = fmaf(xv[ci][k], wg(wc, ci * 9 + k), acc);
      ys[c][yr][yc] = acc;
    }
  }
  __syncthreads();

  // ---- Phase C: lane=pixel (waves 0-1), serial o-loop, SGPR weights ----
  if (tid < TH * TW) {
    int row = tid >> 5;                  // 0..3
    int col = tid & 31;                  // 0..31
    int i = ti0 + row, j = tj0 + col;

    float tv[CIN][9];                    // own pixel's taps, per-lane reads
#pragma unroll
    for (int c = 0; c < CIN; ++c)
#pragma unroll
      for (int kh = 0; kh < 3; ++kh)
#pragma unroll
        for (int kw = 0; kw < 3; ++kw)
          tv[c][kh * 3 + kw] = ys[c][row + kh][col + kw];

    bool v1h = (i + 1) < OH, v2h = (i + 2) < OH;
    bool v1w = (j + 1) < OW, v2w = (j + 2) < OW;
    bool vt[9] = {true, v1w, v2w,
                  v1h, v1h && v1w, v1h && v2w,
                  v2h, v2h && v1w, v2h && v2w};

    const float NI = -__builtin_inff();
    float mn = __builtin_inff();

#pragma unroll 1
    for (int o = 0; o < COUT; ++o) {     // 72 weight SGPRs live per iter
      W72 wo = sload_w72(w + o * (CIN * 9));
      float mx = NI;
#pragma unroll
      for (int k = 0; k < 9; ++k) {
        float p0 = tv[0][k] * wg(wo, 0 * 9 + k);
        float p1 = tv[1][k] * wg(wo, 1 * 9 + k);
        float p2 = tv[2][k] * wg(wo, 2 * 9 + k);
        float p3 = tv[3][k] * wg(wo, 3 * 9 + k);
        float p4 = tv[4][k] * wg(wo, 4 * 9 + k);
        float p5 = tv[5][k] * wg(wo, 5 * 9 + k);
        float p6 = tv[6][k] * wg(wo, 6 * 9 + k);
        float p7 = tv[7][k] * wg(wo, 7 * 9 + k);
        float t0 = fmaxf(fmaxf(p0, p1), p2);   // 3-ary -> v_max3
        float t1 = fmaxf(fmaxf(p3, p4), p5);
        float t2 = fmaxf(p6, p7);
        float mk = fmaxf(fmaxf(t0, t1), t2);
        float z  = vt[k] ? mk : NI;            // vt[0]=true folds away
        mx = (k == 0) ? z : fmaxf(mx, z);
      }
      mn = fminf(mn, mx);
    }

    if (i < OH && j < OW) out[(b * OH + i) * OW + j] = 2.0f * mn;
  }
}

extern "C" void kernel_launch(void* const* d_in, const int* in_sizes, int n_in,
                              void* d_out, int out_size, void* d_ws, size_t ws_size,
                              hipStream_t stream) {
  const float* x    = (const float*)d_in[0];  // (8,8,128,128)
  const float* w    = (const float*)d_in[1];  // (32,8,3,3)
  const float* bias = (const float*)d_in[2];  // (32,)
  float* out = (float*)d_out;                 // (8,1,126,126) fp32

  const int blocks = B_ * NTI * NTJ;          // 1024 tiles
  fused_kernel<<<blocks, 256, 0, stream>>>(x, w, bias, out);
}

// Round 19
// 79.532 us; speedup vs baseline: 2.4931x; 1.0480x over previous
//
#include <hip/hip_runtime.h>

#define B_   8
#define CIN  8
#define COUT 32
#define H_   128
#define W_   128
#define OH   126
#define OW   126
#define TW   32
#define TH   4
#define XW   (TW + 4)   // 36
#define XH   (TH + 4)   // 8
#define YW   (TW + 2)   // 34
#define YH   (TH + 2)   // 6
#define NTJ  4
#define NTI  32
#define NPIXT (TH * TW) // 128

// Forced scalar-pipe weight loads (R16: kernel ~33us). R17 crash diagnosis:
// plain "=s" outputs in a MULTI-instruction asm block may be allocated
// overlapping the input pointer %5 -> first s_load clobbers the address the
// later s_loads use -> wild SMEM reads -> GPU fault. Fix: early-clobber "=&s"
// so outputs and inputs are disjoint (cf. learn_hip r282 early-clobber note).
typedef __attribute__((ext_vector_type(16))) float fx16;
typedef __attribute__((ext_vector_type(8)))  float fx8;
struct W72 { fx16 a, b, c, d; fx8 e; };

__device__ __forceinline__ W72 sload_w72(const float* p) {
  W72 r;
  asm volatile(
      "s_load_dwordx16 %0, %5, 0x0\n\t"
      "s_load_dwordx16 %1, %5, 0x40\n\t"
      "s_load_dwordx16 %2, %5, 0x80\n\t"
      "s_load_dwordx16 %3, %5, 0xc0\n\t"
      "s_load_dwordx8  %4, %5, 0x100\n\t"
      "s_waitcnt lgkmcnt(0)"
      : "=&s"(r.a), "=&s"(r.b), "=&s"(r.c), "=&s"(r.d), "=&s"(r.e)
      : "s"(p));
  return r;
}
__device__ __forceinline__ float wg(const W72& w, int k) {  // k const after unroll
  return k < 16 ? w.a[k]
       : k < 32 ? w.b[k - 16]
       : k < 48 ? w.c[k - 32]
       : k < 64 ? w.d[k - 48]
                : w.e[k - 64];
}

__global__ __launch_bounds__(256) void fused_kernel(
    const float* __restrict__ x, const float* __restrict__ w,
    const float* __restrict__ bias, float* __restrict__ out) {
  __shared__ float xs[CIN][XH][XW];   // 9216 B
  __shared__ float ys[CIN][YH][YW];   // 6528 B channel-major
  __shared__ float bs[CIN];           // 32 B
  __shared__ float red[NPIXT];        // 512 B

  int tid = threadIdx.x;
  int blk = blockIdx.x;
  int tj0 = (blk % NTJ) * TW;
  int ti0 = ((blk / NTJ) % NTI) * TH;
  int b   = blk / (NTJ * NTI);

  // ---- Phase A: stage x tile (+bias) ----
  const float* xb = x + (long)b * CIN * H_ * W_;
#pragma unroll 1
  for (int e = tid; e < CIN * XH * XW; e += 256) {
    int cc = e % XW;
    int rr = (e / XW) % XH;
    int ci = e / (XW * XH);
    int gi = ti0 + rr; if (gi > H_ - 1) gi = H_ - 1;  // clamp (masked later)
    int gj = tj0 + cc; if (gj > W_ - 1) gj = W_ - 1;
    xs[ci][rr][cc] = xb[(ci * H_ + gi) * W_ + gj];
  }
  if (tid < CIN) bs[tid] = bias[tid];
  __syncthreads();

  // ---- Phase B: conv + bias -> ys; lane=pixel, weights via s_load ----
  if (tid < YH * YW) {
    int yr = tid / YW;
    int yc = tid % YW;
    float xv[CIN][9];
#pragma unroll
    for (int ci = 0; ci < CIN; ++ci)
#pragma unroll
      for (int kh = 0; kh < 3; ++kh)
#pragma unroll
        for (int kw = 0; kw < 3; ++kw)
          xv[ci][kh * 3 + kw] = xs[ci][yr + kh][yc + kw];

#pragma unroll 1
    for (int c = 0; c < CIN; ++c) {       // 72 weight SGPRs live per iter
      W72 wc = sload_w72(w + c * (CIN * 9));
      float acc = bs[c];
#pragma unroll
      for (int ci = 0; ci < CIN; ++ci)
#pragma unroll
        for (int k = 0; k < 9; ++k)
          acc = fmaf(xv[ci][k], wg(wc, ci * 9 + k), acc);
      ys[c][yr][yc] = acc;
    }
  }
  __syncthreads();

  // ---- Phase C: all 256 threads; 2 threads/pixel, 16 o's each ----
  int pix  = tid & (NPIXT - 1);                         // 0..127
  int half = __builtin_amdgcn_readfirstlane(tid >> 7);  // wave-uniform 0/1
  int row = pix >> 5;                  // 0..3
  int col = pix & 31;                  // 0..31
  int i = ti0 + row, j = tj0 + col;

  float tv[CIN][9];                    // own pixel's taps, per-lane reads
#pragma unroll
  for (int c = 0; c < CIN; ++c)
#pragma unroll
    for (int kh = 0; kh < 3; ++kh)
#pragma unroll
      for (int kw = 0; kw < 3; ++kw)
        tv[c][kh * 3 + kw] = ys[c][row + kh][col + kw];

  bool v1h = (i + 1) < OH, v2h = (i + 2) < OH;
  bool v1w = (j + 1) < OW, v2w = (j + 2) < OW;
  bool vt[9] = {true, v1w, v2w,
                v1h, v1h && v1w, v1h && v2w,
                v2h, v2h && v1w, v2h && v2w};

  const float NI = -__builtin_inff();
  float mn = __builtin_inff();

#pragma unroll 1
  for (int oo = 0; oo < COUT / 2; ++oo) {   // 16 serial o's per half
    W72 wo = sload_w72(w + (half * (COUT / 2) + oo) * (CIN * 9));
    float mx = NI;
#pragma unroll
    for (int k = 0; k < 9; ++k) {
      float p0 = tv[0][k] * wg(wo, 0 * 9 + k);
      float p1 = tv[1][k] * wg(wo, 1 * 9 + k);
      float p2 = tv[2][k] * wg(wo, 2 * 9 + k);
      float p3 = tv[3][k] * wg(wo, 3 * 9 + k);
      float p4 = tv[4][k] * wg(wo, 4 * 9 + k);
      float p5 = tv[5][k] * wg(wo, 5 * 9 + k);
      float p6 = tv[6][k] * wg(wo, 6 * 9 + k);
      float p7 = tv[7][k] * wg(wo, 7 * 9 + k);
      float t0 = fmaxf(fmaxf(p0, p1), p2);   // 3-ary -> v_max3
      float t1 = fmaxf(fmaxf(p3, p4), p5);
      float t2 = fmaxf(p6, p7);
      float mk = fmaxf(fmaxf(t0, t1), t2);
      float z  = vt[k] ? mk : NI;            // vt[0]=true folds away
      mx = (k == 0) ? z : fmaxf(mx, z);
    }
    mn = fminf(mn, mx);
  }

  // pairwise min-reduce across the two halves
  if (half == 1) red[pix] = mn;
  __syncthreads();
  if (half == 0) {
    float r = fminf(mn, red[pix]);
    if (i < OH && j < OW) out[(b * OH + i) * OW + j] = 2.0f * r;
  }
}

extern "C" void kernel_launch(void* const* d_in, const int* in_sizes, int n_in,
                              void* d_out, int out_size, void* d_ws, size_t ws_size,
                              hipStream_t stream) {
  const float* x    = (const float*)d_in[0];  // (8,8,128,128)
  const float* w    = (const float*)d_in[1];  // (32,8,3,3)
  const float* bias = (const float*)d_in[2];  // (32,)
  float* out = (float*)d_out;                 // (8,1,126,126) fp32

  const int blocks = B_ * NTI * NTJ;          // 1024 tiles
  fused_kernel<<<blocks, 256, 0, stream>>>(x, w, bias, out);
}